// Round 9
// baseline (84940.790 us; speedup 1.0000x reference)
//
#include <hip/hip_runtime.h>
#include <hip/hip_bf16.h>

#define HDIM 96
#define G4   384
#define LSEQ 32768
#define BATCH 8

__device__ __forceinline__ float sigm_(float x) { return 1.f / (1.f + __expf(-x)); }
__device__ __forceinline__ float tanh_(float x) { return 2.f / (1.f + __expf(-2.f * x)) - 1.f; }

// Pin a row-triple of float4s (12 floats) so the allocator cannot remat/spill.
#define PIN4x3(A,B,C) asm volatile("" : \
  "+v"(A.x),"+v"(A.y),"+v"(A.z),"+v"(A.w), \
  "+v"(B.x),"+v"(B.y),"+v"(B.z),"+v"(B.w), \
  "+v"(C.x),"+v"(C.y),"+v"(C.z),"+v"(C.w));

// 4 gate-row dot-product segments; 4 independent accumulator chains.
#define MVK(n, hv) \
  gi=fmaf(wI##n.x,hv.x,gi); gi=fmaf(wI##n.y,hv.y,gi); gi=fmaf(wI##n.z,hv.z,gi); gi=fmaf(wI##n.w,hv.w,gi); \
  gf=fmaf(wF##n.x,hv.x,gf); gf=fmaf(wF##n.y,hv.y,gf); gf=fmaf(wF##n.z,hv.z,gf); gf=fmaf(wF##n.w,hv.w,gf); \
  gg=fmaf(wG##n.x,hv.x,gg); gg=fmaf(wG##n.y,hv.y,gg); gg=fmaf(wG##n.z,hv.z,gg); gg=fmaf(wG##n.w,hv.w,gg); \
  go=fmaf(wO##n.x,hv.x,go); go=fmaf(wO##n.y,hv.y,go); go=fmaf(wO##n.z,hv.z,go); go=fmaf(wO##n.w,hv.w,go);

// Butterfly sum over the 8 s-lanes of an element group (xor stays in-group).
#define RED3(v) { v += __shfl_xor(v,4); v += __shfl_xor(v,2); v += __shfl_xor(v,1); }

#define WLOADPIN() \
    const float4* pI = reinterpret_cast<const float4*>(Whh + (size_t)e       *HDIM + 12*s); \
    const float4* pF = reinterpret_cast<const float4*>(Whh + (size_t)(96 +e) *HDIM + 12*s); \
    const float4* pG = reinterpret_cast<const float4*>(Whh + (size_t)(192+e) *HDIM + 12*s); \
    const float4* pO = reinterpret_cast<const float4*>(Whh + (size_t)(288+e) *HDIM + 12*s); \
    float4 wI0=pI[0], wI1=pI[1], wI2=pI[2]; \
    float4 wF0=pF[0], wF1=pF[1], wF2=pF[2]; \
    float4 wG0=pG[0], wG1=pG[1], wG2=pG[2]; \
    float4 wO0=pO[0], wO1=pO[1], wO2=pO[2]; \
    PIN4x3(wI0,wI1,wI2) PIN4x3(wF0,wF1,wF2) PIN4x3(wG0,wG1,wG2) PIN4x3(wO0,wO1,wO2)

// ---------------------------------------------------------------------------
// Scan layer 0: 768 threads. tid = e*8+s: element e (0..95), col-seg s (0..7,
// 12 cols). Thread owns rows (e, 96+e, 192+e, 288+e) x cols [12s,12s+12).
// Per step: 3 broadcast ds_read_b128 (h), 48 FMA, shfl_xor-reduce over the 8
// s-lanes, s==0 lane activates + updates c (register) + publishes h to a
// double-buffered LDS slab. ONE barrier per step.
// ---------------------------------------------------------------------------
__global__ void __launch_bounds__(768)
__attribute__((amdgpu_waves_per_eu(3, 3)))
lstm_scan0(const float* __restrict__ x,
           const float* __restrict__ Wih,
           const float* __restrict__ Whh,
           const float* __restrict__ bvec,
           const float* __restrict__ h0v,
           const float* __restrict__ c0v,
           float* __restrict__ hout)
{
    const int bidx = blockIdx.x;
    const int tid  = threadIdx.x;
    const int e    = tid >> 3;
    const int s    = tid & 7;

    __shared__ __align__(16) float hs[2 * HDIM];

    WLOADPIN()

    float wiI=0.f,wiF=0.f,wiG=0.f,wiO=0.f, bbI=0.f,bbF=0.f,bbG=0.f,bbO=0.f, cU=0.f;
    if (s == 0) {
        wiI = Wih[e];      wiF = Wih[96+e];  wiG = Wih[192+e]; wiO = Wih[288+e];
        bbI = bvec[e];     bbF = bvec[96+e]; bbG = bvec[192+e]; bbO = bvec[288+e];
        cU  = c0v[e];
        hs[e] = h0v[e];
    }
    __syncthreads();

    const float* xb  = x + (size_t)bidx * LSEQ;
    float*       hob = hout + (size_t)bidx * LSEQ * HDIM;
    float xA = xb[0];
    float xB = xb[1];

#define STEP0(RBASE, WBASE, TT_, XV) { \
    const float4* hp = reinterpret_cast<const float4*>(hs + (RBASE) + 12*s); \
    float4 hv0 = hp[0], hv1 = hp[1], hv2 = hp[2]; \
    float gi=0.f, gf=0.f, gg=0.f, go=0.f; \
    MVK(0,hv0) MVK(1,hv1) MVK(2,hv2) \
    RED3(gi) RED3(gf) RED3(gg) RED3(go) \
    int tpre = (TT_) + 2; if (tpre > LSEQ-1) tpre = LSEQ-1; \
    float xn = xb[tpre]; \
    if (s == 0) { \
        gi = fmaf(wiI,(XV),gi+bbI); gf = fmaf(wiF,(XV),gf+bbF); \
        gg = fmaf(wiG,(XV),gg+bbG); go = fmaf(wiO,(XV),go+bbO); \
        float si=sigm_(gi), sf=sigm_(gf), tg=tanh_(gg), so=sigm_(go); \
        cU = fmaf(sf, cU, si*tg); \
        float hN = so * tanh_(cU); \
        hs[(WBASE) + e] = hN; \
        hob[(size_t)(TT_)*HDIM + e] = hN; \
    } \
    (XV) = xn; \
    __syncthreads(); }

#pragma unroll 1
    for (int t = 0; t < LSEQ; t += 2) {
        STEP0(0,    HDIM, t,     xA)
        STEP0(HDIM, 0,    t + 1, xB)
    }
#undef STEP0
}

// ---------------------------------------------------------------------------
// Scan layer 1 + chunked carry. xp is laid out (t, elem, gate) as float4 so
// the s==0 lane does ONE 16B load per step.
// ---------------------------------------------------------------------------
__global__ void __launch_bounds__(768)
__attribute__((amdgpu_waves_per_eu(3, 3)))
lstm_scan1(const float* __restrict__ xpq,   // (B,T,96,4): [i,f,g,o] per elem
           const float* __restrict__ Whh,
           const float* __restrict__ h0v,
           const float* __restrict__ c0v,
           float* __restrict__ carry,       // (B,192): h[0..95], c[96..191]
           float* __restrict__ h1out,       // (B,T,96)
           int chunk, int T)
{
    const int bidx = blockIdx.x;
    const int tid  = threadIdx.x;
    const int e    = tid >> 3;
    const int s    = tid & 7;

    __shared__ __align__(16) float hs[2 * HDIM];

    WLOADPIN()

    float* cb = carry + bidx * 2 * HDIM;
    float cU = 0.f, hLast = 0.f;
    if (s == 0) {
        float hI;
        if (chunk == 0) { hI = h0v[HDIM + e]; cU = c0v[HDIM + e]; }
        else            { hI = cb[e];         cU = cb[HDIM + e]; }
        hs[e] = hI;
        hLast = hI;
    }
    __syncthreads();

    const float* xq  = xpq + ((size_t)bidx * T) * G4 + e * 4;
    float*       hb1 = h1out + (size_t)bidx * T * HDIM;

    float4 xp4 = make_float4(0.f, 0.f, 0.f, 0.f);
    if (s == 0) xp4 = *reinterpret_cast<const float4*>(xq);

#define STEP1(RBASE, WBASE, TT_) { \
    const float4* hp = reinterpret_cast<const float4*>(hs + (RBASE) + 12*s); \
    float4 hv0 = hp[0], hv1 = hp[1], hv2 = hp[2]; \
    float gi=0.f, gf=0.f, gg=0.f, go=0.f; \
    MVK(0,hv0) MVK(1,hv1) MVK(2,hv2) \
    RED3(gi) RED3(gf) RED3(gg) RED3(go) \
    float4 xpn = xp4; \
    if (s == 0) { \
        int tn = (TT_) + 1; if (tn > T-1) tn = T-1; \
        xpn = *reinterpret_cast<const float4*>(xq + (size_t)tn * G4); \
        gi += xp4.x; gf += xp4.y; gg += xp4.z; go += xp4.w; \
        float si=sigm_(gi), sf=sigm_(gf), tg=tanh_(gg), so=sigm_(go); \
        cU = fmaf(sf, cU, si*tg); \
        float hN = so * tanh_(cU); \
        hLast = hN; \
        hs[(WBASE) + e] = hN; \
        hb1[(size_t)(TT_)*HDIM + e] = hN; \
    } \
    xp4 = xpn; \
    __syncthreads(); }

#pragma unroll 1
    for (int t = 0; t < T; t += 2) {
        STEP1(0,    HDIM, t)
        STEP1(HDIM, 0,    t + 1)
    }
#undef STEP1

    if (s == 0) { cb[e] = hLast; cb[HDIM + e] = cU; }
}

// ---------------------------------------------------------------------------
// Layer-1 input projection, bias folded, output layout (t, elem, gate).
// ---------------------------------------------------------------------------
#define W24(F) F(0) F(1) F(2) F(3) F(4) F(5) F(6) F(7) F(8) F(9) F(10) F(11) \
               F(12) F(13) F(14) F(15) F(16) F(17) F(18) F(19) F(20) F(21) F(22) F(23)

__global__ __launch_bounds__(384, 1)
void xp_gemm(const float* __restrict__ hin,
             const float* __restrict__ Wih,
             const float* __restrict__ bvec,
             float* __restrict__ xp,        // (B,T,96,4)
             int t0, int T)
{
    const int TT = 32;
    const int ntb = T / TT;
    const int b  = blockIdx.x / ntb;
    const int tb = blockIdx.x % ntb;
    const int g  = threadIdx.x;
    const int q  = g / 96;      // gate index
    const int el = g % 96;      // element

    __shared__ __align__(16) float h_sh[TT * HDIM];

    const float4* W0p = reinterpret_cast<const float4*>(Wih + g * HDIM);
#define XDECL(n) float4 v_##n;
#define XLOAD(n) v_##n = W0p[n];
    W24(XDECL)
    W24(XLOAD)
    const float bias = bvec[g];

    const float* src = hin + ((size_t)b * LSEQ + t0 + (size_t)tb * TT) * HDIM;
    for (int i = g; i < TT * HDIM; i += G4) h_sh[i] = src[i];
    __syncthreads();

    float* dst = xp + ((size_t)b * T + (size_t)tb * TT) * G4 + el * 4 + q;
    for (int tt = 0; tt < TT; ++tt) {
        const float4* h4 = reinterpret_cast<const float4*>(h_sh + tt * HDIM);
        float acc0 = bias, acc1 = 0.f, acc2 = 0.f, acc3 = 0.f;
#define XFMA(n) { float4 hv = h4[n]; \
        acc0 = fmaf(v_##n.x, hv.x, acc0); acc1 = fmaf(v_##n.y, hv.y, acc1); \
        acc2 = fmaf(v_##n.z, hv.z, acc2); acc3 = fmaf(v_##n.w, hv.w, acc3); }
        W24(XFMA)
        dst[(size_t)tt * G4] = (acc0 + acc1) + (acc2 + acc3);
    }
}

// ---------------------------------------------------------------------------
// Head GEMV: out[b][t] = h1[b][t][:] . head_w + head_b
// ---------------------------------------------------------------------------
__global__ __launch_bounds__(256, 1)
void head_gemv(const float* __restrict__ h1,
               const float* __restrict__ head_w,
               const float* __restrict__ head_b,
               float* __restrict__ out,
               int chunk, int T)
{
    const int idx  = blockIdx.x * 4 + (threadIdx.x >> 6);
    const int lane = threadIdx.x & 63;
    const int b = idx / T;
    const int t = idx % T;

    const float* hp = h1 + ((size_t)b * T + t) * HDIM;
    float s = hp[lane] * head_w[lane];
    if (lane < 32) s = fmaf(hp[64 + lane], head_w[64 + lane], s);
    s += __shfl_down(s, 32);
    s += __shfl_down(s, 16);
    s += __shfl_down(s, 8);
    s += __shfl_down(s, 4);
    s += __shfl_down(s, 2);
    s += __shfl_down(s, 1);
    if (lane == 0) out[(size_t)b * LSEQ + (size_t)chunk * T + t] = s + head_b[0];
}

// ---------------------------------------------------------------------------
extern "C" void kernel_launch(void* const* d_in, const int* in_sizes, int n_in,
                              void* d_out, int out_size, void* d_ws, size_t ws_size,
                              hipStream_t stream)
{
    const float* x     = (const float*)d_in[0];
    const float* Wih0  = (const float*)d_in[1];
    const float* Whh0  = (const float*)d_in[2];
    const float* b0    = (const float*)d_in[3];
    const float* Wih1  = (const float*)d_in[4];
    const float* Whh1  = (const float*)d_in[5];
    const float* b1    = (const float*)d_in[6];
    const float* h0    = (const float*)d_in[7];
    const float* c0    = (const float*)d_in[8];
    const float* headw = (const float*)d_in[9];
    const float* headb = (const float*)d_in[10];
    float* out = (float*)d_out;

    char* ws = (char*)d_ws;
    const size_t h0bytes = (size_t)BATCH * LSEQ * HDIM * sizeof(float); // 100.7 MB

    int T = 4096;
    while (T > 512) {
        size_t need = h0bytes
                    + (size_t)T * BATCH * G4 * sizeof(float)
                    + (size_t)T * BATCH * HDIM * sizeof(float)
                    + 8192;
        if (need <= ws_size) break;
        T >>= 1;
    }

    float* h0buf = (float*)ws;
    float* xpbuf = (float*)(ws + h0bytes);
    float* h1buf = (float*)(ws + h0bytes + (size_t)T * BATCH * G4 * sizeof(float));
    float* carry = (float*)(ws + h0bytes + (size_t)T * BATCH * G4 * sizeof(float)
                               + (size_t)T * BATCH * HDIM * sizeof(float));

    lstm_scan0<<<BATCH, 768, 0, stream>>>(x, Wih0, Whh0, b0, h0, c0, h0buf);

    const int nch = LSEQ / T;
    for (int ch = 0; ch < nch; ++ch) {
        xp_gemm<<<BATCH * (T / 32), G4, 0, stream>>>(h0buf, Wih1, b1, xpbuf, ch * T, T);
        lstm_scan1<<<BATCH, 768, 0, stream>>>(xpbuf, Whh1, h0, c0, carry, h1buf, ch, T);
        head_gemv<<<BATCH * T / 4, 256, 0, stream>>>(h1buf, headw, headb, out, ch, T);
    }
}

// Round 10
// 42444.336 us; speedup vs baseline: 2.0012x; 2.0012x over previous
//
#include <hip/hip_runtime.h>

#define HDIM 96
#define G4   384
#define LSEQ 32768
#define BATCH 8
#define TCH   1024
#define NCH   (LSEQ / TCH)

__device__ __forceinline__ float RDL(float v, int l) {
    return __uint_as_float(__builtin_amdgcn_readlane(__float_as_uint(v), l));
}
__device__ __forceinline__ float tanh_(float x) { return 2.f / (1.f + __expf(-2.f * x)) - 1.f; }

// ---- round-8 scan macros: row-pair (rp, rp+192) x 24 cols, readlane bcast ----
#define W6(F) F(0) F(1) F(2) F(3) F(4) F(5)
#define WDECL(n) float4 wA_##n, wB_##n;
#define WLOAD(n) wA_##n = WA[n]; wB_##n = WB[n];
#define WPIN(n)  asm volatile("" : "+v"(wA_##n.x), "+v"(wA_##n.y), "+v"(wA_##n.z), "+v"(wA_##n.w), \
                                   "+v"(wB_##n.x), "+v"(wB_##n.y), "+v"(wB_##n.z), "+v"(wB_##n.w));
#define MV(n) { \
    float h0_=RDL(hU,4*n+0), h1_=RDL(hU,4*n+1), h2_=RDL(hU,4*n+2), h3_=RDL(hU,4*n+3); \
    a0  = fmaf(wA_##n.x, h0_, a0);  a1  = fmaf(wB_##n.x, h0_, a1); \
    a0b = fmaf(wA_##n.y, h1_, a0b); a1b = fmaf(wB_##n.y, h1_, a1b); \
    a0  = fmaf(wA_##n.z, h2_, a0);  a1  = fmaf(wB_##n.z, h2_, a1); \
    a0b = fmaf(wA_##n.w, h3_, a0b); a1b = fmaf(wB_##n.w, h3_, a1b); }
#define MV_ALL() MV(0) MV(1) MV(2) MV(3) MV(4) MV(5)

#define PIN4x3(A,B,C) asm volatile("" : \
  "+v"(A.x),"+v"(A.y),"+v"(A.z),"+v"(A.w), \
  "+v"(B.x),"+v"(B.y),"+v"(B.z),"+v"(B.w), \
  "+v"(C.x),"+v"(C.y),"+v"(C.z),"+v"(C.w));

__global__ void init_flags(int* flags) {
    if (threadIdx.x < 16) flags[threadIdx.x] = 0;
}

// ---------------------------------------------------------------------------
// Persistent pipeline: blocks 0-7 = layer-0 scan (producer, per-chunk flag);
// blocks 8-15 = layer-1 consumer (xp GEMM + scan + head per chunk).
// Scan cores are the round-8 structure verbatim (two barriers, readlane).
// ---------------------------------------------------------------------------
__global__ void __launch_bounds__(768)
__attribute__((amdgpu_waves_per_eu(3, 3)))
lstm_pipe(const float* __restrict__ x,
          const float* __restrict__ Wih0, const float* __restrict__ Whh0, const float* __restrict__ b0v,
          const float* __restrict__ Wih1, const float* __restrict__ Whh1, const float* __restrict__ b1v,
          const float* __restrict__ h0v,  const float* __restrict__ c0v,
          const float* __restrict__ headw,const float* __restrict__ headb,
          float* __restrict__ h0buf, float* __restrict__ xpbuf, float* __restrict__ h1buf,
          int* flags, float* __restrict__ out)
{
    const int tid  = threadIdx.x;
    const int lane = tid & 63;
    const int wid  = tid >> 6;
    const int colseg = wid / 3;                 // 0..3 (24-col segment)
    const int rp   = (wid % 3) * 64 + lane;     // row-pair id 0..191
    const int cs   = colseg * 24;
    const bool comb = (wid < 3);
    const int e    = cs + ((lane < 24) ? lane : 23);
    const bool hstore = ((wid % 3) == 0) && (lane < 24);

    __shared__ float2 part_sh[3][192];
    __shared__ float  p_sh[96];
    __shared__ float2 fo_sh[96];
    __shared__ __align__(16) float h_sh[32 * HDIM];
    __shared__ float ph_sh[G4];

    if (blockIdx.x < 8) {
        // =================== L0 producer ===================
        const int bidx = blockIdx.x;
        const float4* WA = reinterpret_cast<const float4*>(Whh0 + (size_t)rp * HDIM + cs);
        const float4* WB = reinterpret_cast<const float4*>(Whh0 + (size_t)(rp + 192) * HDIM + cs);
        W6(WDECL) W6(WLOAD) W6(WPIN)

        float bb0 = 0.f, bb1 = 0.f, wi0 = 0.f, wi1 = 0.f;
        if (comb) { bb0 = b0v[rp]; bb1 = b0v[rp + 192]; wi0 = Wih0[rp]; wi1 = Wih0[rp + 192]; }

        float hU = h0v[e];
        float cU = c0v[e];
        const float* xb  = x + (size_t)bidx * LSEQ;
        float*       hob = h0buf + (size_t)bidx * LSEQ * HDIM;
        float xt = xb[0];

#pragma unroll 1
        for (int t = 0; t < LSEQ; ++t) {
            float xnext = (t + 1 < LSEQ) ? xb[t + 1] : 0.f;

            float a0, a1;
            if (comb) { a0 = fmaf(wi0, xt, bb0); a1 = fmaf(wi1, xt, bb1); }
            else      { a0 = 0.f; a1 = 0.f; }
            float a0b = 0.f, a1b = 0.f;
            MV_ALL()
            float g0 = a0 + a0b, g1 = a1 + a1b;

            if (!comb) part_sh[colseg - 1][rp] = make_float2(g0, g1);
            __syncthreads();
            if (comb) {
                float2 q0 = part_sh[0][rp], q1 = part_sh[1][rp], q2 = part_sh[2][rp];
                g0 += (q0.x + q1.x) + q2.x;
                g1 += (q0.y + q1.y) + q2.y;
                float s0 = 1.f / (1.f + __expf(-g0));
                if (rp < 96) {
                    float tg = 2.f / (1.f + __expf(-2.f * g1)) - 1.f;
                    p_sh[rp] = s0 * tg;
                } else {
                    float s1 = 1.f / (1.f + __expf(-g1));
                    fo_sh[rp - 96] = make_float2(s0, s1);
                }
            }
            __syncthreads();

            float  p  = p_sh[e];
            float2 fo = fo_sh[e];
            cU = fmaf(fo.x, cU, p);
            hU = fo.y * tanh_(cU);
            if (hstore) hob[(size_t)t * HDIM + e] = hU;

            if (((t + 1) & (TCH - 1)) == 0) {
                __threadfence();
                __syncthreads();
                if (tid == 0)
                    __hip_atomic_store(&flags[bidx], (t + 1) / TCH,
                                       __ATOMIC_RELEASE, __HIP_MEMORY_SCOPE_AGENT);
            }
            xt = xnext;
        }
    } else {
        // =================== L1 consumer: xp + scan + head ===================
        const int bidx = blockIdx.x - 8;
        const float* hsrcB = h0buf + (size_t)bidx * LSEQ * HDIM;
        float* xpd = xpbuf + (size_t)bidx * TCH * G4;
        float* h1c = h1buf + (size_t)bidx * TCH * HDIM;

        const bool half = (tid >= G4);
        const int  g    = half ? tid - G4 : tid;
        const float4* Wxp = reinterpret_cast<const float4*>(Wih1 + (size_t)g * HDIM + (half ? 48 : 0));
        const float xbias = half ? 0.f : b1v[g];

        const float4* WA = reinterpret_cast<const float4*>(Whh1 + (size_t)rp * HDIM + cs);
        const float4* WB = reinterpret_cast<const float4*>(Whh1 + (size_t)(rp + 192) * HDIM + cs);

        float hU = h0v[HDIM + e];
        float cU = c0v[HDIM + e];

#pragma unroll 1
        for (int k = 0; k < NCH; ++k) {
            if (tid == 0) {
                while (__hip_atomic_load(&flags[bidx], __ATOMIC_ACQUIRE,
                                         __HIP_MEMORY_SCOPE_AGENT) < k + 1)
                    __builtin_amdgcn_s_sleep(2);
            }
            __syncthreads();
            __threadfence();   // invalidate stale cached h0 lines (cross-XCD)

            // ---- xp phase: xp[t][row] = b1[row] + Wih1[row,:] . h0[t,:] ----
            {
                float4 q0=Wxp[0],q1=Wxp[1],q2=Wxp[2],q3=Wxp[3],q4=Wxp[4],q5=Wxp[5],
                       q6=Wxp[6],q7=Wxp[7],q8=Wxp[8],q9=Wxp[9],q10=Wxp[10],q11=Wxp[11];
                PIN4x3(q0,q1,q2) PIN4x3(q3,q4,q5) PIN4x3(q6,q7,q8) PIN4x3(q9,q10,q11)
                const float* hsrc = hsrcB + (size_t)k * TCH * HDIM;
#pragma unroll 1
                for (int t0 = 0; t0 < TCH; t0 += 32) {
                    for (int i = tid; i < 32 * HDIM; i += 768)
                        h_sh[i] = hsrc[(size_t)t0 * HDIM + i];
                    __syncthreads();
#pragma unroll 1
                    for (int tt = 0; tt < 32; ++tt) {
                        const float4* h4 = reinterpret_cast<const float4*>(
                            h_sh + tt * HDIM + (half ? 48 : 0));
                        float a0 = xbias, a1 = 0.f, a2 = 0.f, a3 = 0.f;
                        float4 hv;
                        hv=h4[0];  a0=fmaf(q0.x, hv.x,a0); a1=fmaf(q0.y, hv.y,a1); a2=fmaf(q0.z, hv.z,a2); a3=fmaf(q0.w, hv.w,a3);
                        hv=h4[1];  a0=fmaf(q1.x, hv.x,a0); a1=fmaf(q1.y, hv.y,a1); a2=fmaf(q1.z, hv.z,a2); a3=fmaf(q1.w, hv.w,a3);
                        hv=h4[2];  a0=fmaf(q2.x, hv.x,a0); a1=fmaf(q2.y, hv.y,a1); a2=fmaf(q2.z, hv.z,a2); a3=fmaf(q2.w, hv.w,a3);
                        hv=h4[3];  a0=fmaf(q3.x, hv.x,a0); a1=fmaf(q3.y, hv.y,a1); a2=fmaf(q3.z, hv.z,a2); a3=fmaf(q3.w, hv.w,a3);
                        hv=h4[4];  a0=fmaf(q4.x, hv.x,a0); a1=fmaf(q4.y, hv.y,a1); a2=fmaf(q4.z, hv.z,a2); a3=fmaf(q4.w, hv.w,a3);
                        hv=h4[5];  a0=fmaf(q5.x, hv.x,a0); a1=fmaf(q5.y, hv.y,a1); a2=fmaf(q5.z, hv.z,a2); a3=fmaf(q5.w, hv.w,a3);
                        hv=h4[6];  a0=fmaf(q6.x, hv.x,a0); a1=fmaf(q6.y, hv.y,a1); a2=fmaf(q6.z, hv.z,a2); a3=fmaf(q6.w, hv.w,a3);
                        hv=h4[7];  a0=fmaf(q7.x, hv.x,a0); a1=fmaf(q7.y, hv.y,a1); a2=fmaf(q7.z, hv.z,a2); a3=fmaf(q7.w, hv.w,a3);
                        hv=h4[8];  a0=fmaf(q8.x, hv.x,a0); a1=fmaf(q8.y, hv.y,a1); a2=fmaf(q8.z, hv.z,a2); a3=fmaf(q8.w, hv.w,a3);
                        hv=h4[9];  a0=fmaf(q9.x, hv.x,a0); a1=fmaf(q9.y, hv.y,a1); a2=fmaf(q9.z, hv.z,a2); a3=fmaf(q9.w, hv.w,a3);
                        hv=h4[10]; a0=fmaf(q10.x,hv.x,a0); a1=fmaf(q10.y,hv.y,a1); a2=fmaf(q10.z,hv.z,a2); a3=fmaf(q10.w,hv.w,a3);
                        hv=h4[11]; a0=fmaf(q11.x,hv.x,a0); a1=fmaf(q11.y,hv.y,a1); a2=fmaf(q11.z,hv.z,a2); a3=fmaf(q11.w,hv.w,a3);
                        float part = (a0 + a1) + (a2 + a3);
                        if (half) ph_sh[g] = part;
                        __syncthreads();
                        if (!half) xpd[(size_t)(t0 + tt) * G4 + g] = part + ph_sh[g];
                        __syncthreads();
                    }
                }
            }

            // ---- scan phase (round-8 structure) ----
            {
                W6(WDECL) W6(WLOAD) W6(WPIN)
                float xc0 = 0.f, xc1 = 0.f;
                if (comb) { xc0 = xpd[rp]; xc1 = xpd[rp + 192]; }
#pragma unroll 1
                for (int t = 0; t < TCH; ++t) {
                    float xn0 = 0.f, xn1 = 0.f;
                    if (comb && (t + 1 < TCH)) {
                        const float* nx = xpd + (size_t)(t + 1) * G4;
                        xn0 = nx[rp]; xn1 = nx[rp + 192];
                    }
                    float a0 = comb ? xc0 : 0.f;
                    float a1 = comb ? xc1 : 0.f;
                    float a0b = 0.f, a1b = 0.f;
                    MV_ALL()
                    float g0 = a0 + a0b, g1 = a1 + a1b;

                    if (!comb) part_sh[colseg - 1][rp] = make_float2(g0, g1);
                    __syncthreads();
                    if (comb) {
                        float2 q0 = part_sh[0][rp], q1 = part_sh[1][rp], q2 = part_sh[2][rp];
                        g0 += (q0.x + q1.x) + q2.x;
                        g1 += (q0.y + q1.y) + q2.y;
                        float s0 = 1.f / (1.f + __expf(-g0));
                        if (rp < 96) {
                            float tg = 2.f / (1.f + __expf(-2.f * g1)) - 1.f;
                            p_sh[rp] = s0 * tg;
                        } else {
                            float s1 = 1.f / (1.f + __expf(-g1));
                            fo_sh[rp - 96] = make_float2(s0, s1);
                        }
                    }
                    __syncthreads();

                    float  p  = p_sh[e];
                    float2 fo = fo_sh[e];
                    cU = fmaf(fo.x, cU, p);
                    hU = fo.y * tanh_(cU);
                    if (hstore) h1c[(size_t)t * HDIM + e] = hU;
                    xc0 = xn0; xc1 = xn1;
                }
            }

            // ---- head phase ----
            __syncthreads();
            {
                const float hb = headb[0];
                const float4* wv = reinterpret_cast<const float4*>(headw);
                for (int t = tid; t < TCH; t += 768) {
                    const float4* hp = reinterpret_cast<const float4*>(h1c + (size_t)t * HDIM);
                    float s2 = 0.f;
#pragma unroll
                    for (int j = 0; j < 24; ++j) {
                        float4 a = hp[j], b = wv[j];
                        s2 = fmaf(a.x, b.x, s2); s2 = fmaf(a.y, b.y, s2);
                        s2 = fmaf(a.z, b.z, s2); s2 = fmaf(a.w, b.w, s2);
                    }
                    out[(size_t)bidx * LSEQ + (size_t)k * TCH + t] = s2 + hb;
                }
            }
            __syncthreads();
        }
    }
}

// ---------------------------------------------------------------------------
extern "C" void kernel_launch(void* const* d_in, const int* in_sizes, int n_in,
                              void* d_out, int out_size, void* d_ws, size_t ws_size,
                              hipStream_t stream)
{
    const float* x     = (const float*)d_in[0];
    const float* Wih0  = (const float*)d_in[1];
    const float* Whh0  = (const float*)d_in[2];
    const float* b0    = (const float*)d_in[3];
    const float* Wih1  = (const float*)d_in[4];
    const float* Whh1  = (const float*)d_in[5];
    const float* b1    = (const float*)d_in[6];
    const float* h0    = (const float*)d_in[7];
    const float* c0    = (const float*)d_in[8];
    const float* headw = (const float*)d_in[9];
    const float* headb = (const float*)d_in[10];
    float* out = (float*)d_out;

    char* ws = (char*)d_ws;
    const size_t h0bytes = (size_t)BATCH * LSEQ * HDIM * sizeof(float);  // 100.7 MB
    const size_t xpbytes = (size_t)BATCH * TCH * G4 * sizeof(float);     // 12.6 MB
    const size_t h1bytes = (size_t)BATCH * TCH * HDIM * sizeof(float);   // 3.15 MB

    float* h0buf = (float*)ws;
    float* xpbuf = (float*)(ws + h0bytes);
    float* h1buf = (float*)(ws + h0bytes + xpbytes);
    int*   flags = (int*)  (ws + h0bytes + xpbytes + h1bytes);

    init_flags<<<1, 64, 0, stream>>>(flags);
    lstm_pipe<<<16, 768, 0, stream>>>(x, Wih0, Whh0, b0, Wih1, Whh1, b1,
                                      h0, c0, headw, headb,
                                      h0buf, xpbuf, h1buf, flags, out);
}

// Round 11
// 27894.257 us; speedup vs baseline: 3.0451x; 1.5216x over previous
//
#include <hip/hip_runtime.h>

#define HDIM 96
#define G4   384
#define LSEQ 32768
#define BATCH 8
#define TCH   1024
#define NCH   (LSEQ / TCH)

__device__ __forceinline__ float RDL(float v, int l) {
    return __uint_as_float(__builtin_amdgcn_readlane(__float_as_uint(v), l));
}
__device__ __forceinline__ float tanh_(float x) { return 2.f / (1.f + __expf(-2.f * x)) - 1.f; }

// ---- round-8 scan macros: row-pair (rp, rp+192) x 24 cols, readlane bcast ----
#define W6(F) F(0) F(1) F(2) F(3) F(4) F(5)
#define WDECL(n) float4 wA_##n, wB_##n;
#define WLOAD(n) wA_##n = WA[n]; wB_##n = WB[n];
#define WPIN(n)  asm volatile("" : "+v"(wA_##n.x), "+v"(wA_##n.y), "+v"(wA_##n.z), "+v"(wA_##n.w), \
                                   "+v"(wB_##n.x), "+v"(wB_##n.y), "+v"(wB_##n.z), "+v"(wB_##n.w));
#define MV(n) { \
    float h0_=RDL(hU,4*n+0), h1_=RDL(hU,4*n+1), h2_=RDL(hU,4*n+2), h3_=RDL(hU,4*n+3); \
    a0  = fmaf(wA_##n.x, h0_, a0);  a1  = fmaf(wB_##n.x, h0_, a1); \
    a0b = fmaf(wA_##n.y, h1_, a0b); a1b = fmaf(wB_##n.y, h1_, a1b); \
    a0  = fmaf(wA_##n.z, h2_, a0);  a1  = fmaf(wB_##n.z, h2_, a1); \
    a0b = fmaf(wA_##n.w, h3_, a0b); a1b = fmaf(wB_##n.w, h3_, a1b); }
#define MV_ALL() MV(0) MV(1) MV(2) MV(3) MV(4) MV(5)

#define PIN4x3(A,B,C) asm volatile("" : \
  "+v"(A.x),"+v"(A.y),"+v"(A.z),"+v"(A.w), \
  "+v"(B.x),"+v"(B.y),"+v"(B.z),"+v"(B.w), \
  "+v"(C.x),"+v"(C.y),"+v"(C.z),"+v"(C.w));

#define WAIT_GE(PTR, VAL) \
    while (__hip_atomic_load((PTR), __ATOMIC_ACQUIRE, __HIP_MEMORY_SCOPE_AGENT) < (VAL)) \
        __builtin_amdgcn_s_sleep(2);

#define SIGNAL(PTR, VAL) \
    __hip_atomic_store((PTR), (VAL), __ATOMIC_RELEASE, __HIP_MEMORY_SCOPE_AGENT);

__global__ void init_flags(int* flags) {
    if (threadIdx.x < 64) flags[threadIdx.x] = 0;
}

// ---------------------------------------------------------------------------
// 32 blocks, 4 roles:
//   0..7   producer  : L0 scan -> h0buf, flag0[b] per TCH chunk
//   8..15  xp worker  : flag0 -> xp ring (depth 2), flag1
//   16..23 consumer   : flag1 -> L1 scan only -> h1 ring, flag2
//   24..31 head       : flag2 -> out, flag3 (ring reuse)
// ---------------------------------------------------------------------------
__global__ void __launch_bounds__(768)
__attribute__((amdgpu_waves_per_eu(3, 3)))
lstm_pipe(const float* __restrict__ x,
          const float* __restrict__ Wih0, const float* __restrict__ Whh0, const float* __restrict__ b0v,
          const float* __restrict__ Wih1, const float* __restrict__ Whh1, const float* __restrict__ b1v,
          const float* __restrict__ h0v,  const float* __restrict__ c0v,
          const float* __restrict__ headw,const float* __restrict__ headb,
          float* __restrict__ h0buf, float* __restrict__ xpbuf, float* __restrict__ h1buf,
          int* flags, float* __restrict__ out)
{
    const int tid  = threadIdx.x;
    const int lane = tid & 63;
    const int wid  = tid >> 6;
    const int colseg = wid / 3;
    const int rp   = (wid % 3) * 64 + lane;
    const int cs   = colseg * 24;
    const bool comb = (wid < 3);
    const int e    = cs + ((lane < 24) ? lane : 23);
    const bool hstore = ((wid % 3) == 0) && (lane < 24);

    int* flag0 = flags;
    int* flag1 = flags + 8;
    int* flag2 = flags + 16;
    int* flag3 = flags + 24;

    __shared__ float2 part_sh[3][192];
    __shared__ float  p_sh[96];
    __shared__ float2 fo_sh[96];
    __shared__ __align__(16) float h_sh[32 * HDIM];
    __shared__ float ph_sh[G4];

    const int role = blockIdx.x >> 3;
    const int bidx = blockIdx.x & 7;

    if (role == 0) {
        // =================== producer: L0 scan ===================
        const float4* WA = reinterpret_cast<const float4*>(Whh0 + (size_t)rp * HDIM + cs);
        const float4* WB = reinterpret_cast<const float4*>(Whh0 + (size_t)(rp + 192) * HDIM + cs);
        W6(WDECL) W6(WLOAD) W6(WPIN)

        float bb0 = 0.f, bb1 = 0.f, wi0 = 0.f, wi1 = 0.f;
        if (comb) { bb0 = b0v[rp]; bb1 = b0v[rp + 192]; wi0 = Wih0[rp]; wi1 = Wih0[rp + 192]; }

        float hU = h0v[e];
        float cU = c0v[e];
        const float* xb  = x + (size_t)bidx * LSEQ;
        float*       hob = h0buf + (size_t)bidx * LSEQ * HDIM;
        float xt = xb[0];

#pragma unroll 1
        for (int t = 0; t < LSEQ; ++t) {
            float xnext = (t + 1 < LSEQ) ? xb[t + 1] : 0.f;

            float a0, a1;
            if (comb) { a0 = fmaf(wi0, xt, bb0); a1 = fmaf(wi1, xt, bb1); }
            else      { a0 = 0.f; a1 = 0.f; }
            float a0b = 0.f, a1b = 0.f;
            MV_ALL()
            float g0 = a0 + a0b, g1 = a1 + a1b;

            if (!comb) part_sh[colseg - 1][rp] = make_float2(g0, g1);
            __syncthreads();
            if (comb) {
                float2 q0 = part_sh[0][rp], q1 = part_sh[1][rp], q2 = part_sh[2][rp];
                g0 += (q0.x + q1.x) + q2.x;
                g1 += (q0.y + q1.y) + q2.y;
                float s0 = 1.f / (1.f + __expf(-g0));
                if (rp < 96) {
                    float tg = 2.f / (1.f + __expf(-2.f * g1)) - 1.f;
                    p_sh[rp] = s0 * tg;
                } else {
                    float s1 = 1.f / (1.f + __expf(-g1));
                    fo_sh[rp - 96] = make_float2(s0, s1);
                }
            }
            __syncthreads();

            float  p  = p_sh[e];
            float2 fo = fo_sh[e];
            cU = fmaf(fo.x, cU, p);
            hU = fo.y * tanh_(cU);
            if (hstore) hob[(size_t)t * HDIM + e] = hU;

            if (((t + 1) & (TCH - 1)) == 0) {
                __threadfence();
                __syncthreads();
                if (tid == 0) SIGNAL(&flag0[bidx], (t + 1) / TCH)
            }
            xt = xnext;
        }
    } else if (role == 1) {
        // =================== xp worker ===================
        const bool halfx = (tid >= G4);
        const int  g     = halfx ? tid - G4 : tid;
        const float4* Wxp = reinterpret_cast<const float4*>(Wih1 + (size_t)g * HDIM + (halfx ? 48 : 0));
        const float xbias = halfx ? 0.f : b1v[g];

        float4 q0=Wxp[0],q1=Wxp[1],q2=Wxp[2],q3=Wxp[3],q4=Wxp[4],q5=Wxp[5],
               q6=Wxp[6],q7=Wxp[7],q8=Wxp[8],q9=Wxp[9],q10=Wxp[10],q11=Wxp[11];
        PIN4x3(q0,q1,q2) PIN4x3(q3,q4,q5) PIN4x3(q6,q7,q8) PIN4x3(q9,q10,q11)

        const float* hsrcB = h0buf + (size_t)bidx * LSEQ * HDIM;

#pragma unroll 1
        for (int k = 0; k < NCH; ++k) {
            if (tid == 0) {
                WAIT_GE(&flag0[bidx], k + 1)
                if (k >= 2) WAIT_GE(&flag2[bidx], k - 1)   // slot k%2 free
            }
            __syncthreads();
            __threadfence();

            const float* hsrc = hsrcB + (size_t)k * TCH * HDIM;
            float* xpd = xpbuf + ((size_t)bidx * 2 + (k & 1)) * TCH * G4;

#pragma unroll 1
            for (int t0 = 0; t0 < TCH; t0 += 32) {
                for (int i = tid; i < 32 * HDIM; i += 768)
                    h_sh[i] = hsrc[(size_t)t0 * HDIM + i];
                __syncthreads();
#pragma unroll 1
                for (int tt = 0; tt < 32; ++tt) {
                    const float4* h4 = reinterpret_cast<const float4*>(
                        h_sh + tt * HDIM + (halfx ? 48 : 0));
                    float a0 = xbias, a1 = 0.f, a2 = 0.f, a3 = 0.f;
                    float4 hv;
                    hv=h4[0];  a0=fmaf(q0.x, hv.x,a0); a1=fmaf(q0.y, hv.y,a1); a2=fmaf(q0.z, hv.z,a2); a3=fmaf(q0.w, hv.w,a3);
                    hv=h4[1];  a0=fmaf(q1.x, hv.x,a0); a1=fmaf(q1.y, hv.y,a1); a2=fmaf(q1.z, hv.z,a2); a3=fmaf(q1.w, hv.w,a3);
                    hv=h4[2];  a0=fmaf(q2.x, hv.x,a0); a1=fmaf(q2.y, hv.y,a1); a2=fmaf(q2.z, hv.z,a2); a3=fmaf(q2.w, hv.w,a3);
                    hv=h4[3];  a0=fmaf(q3.x, hv.x,a0); a1=fmaf(q3.y, hv.y,a1); a2=fmaf(q3.z, hv.z,a2); a3=fmaf(q3.w, hv.w,a3);
                    hv=h4[4];  a0=fmaf(q4.x, hv.x,a0); a1=fmaf(q4.y, hv.y,a1); a2=fmaf(q4.z, hv.z,a2); a3=fmaf(q4.w, hv.w,a3);
                    hv=h4[5];  a0=fmaf(q5.x, hv.x,a0); a1=fmaf(q5.y, hv.y,a1); a2=fmaf(q5.z, hv.z,a2); a3=fmaf(q5.w, hv.w,a3);
                    hv=h4[6];  a0=fmaf(q6.x, hv.x,a0); a1=fmaf(q6.y, hv.y,a1); a2=fmaf(q6.z, hv.z,a2); a3=fmaf(q6.w, hv.w,a3);
                    hv=h4[7];  a0=fmaf(q7.x, hv.x,a0); a1=fmaf(q7.y, hv.y,a1); a2=fmaf(q7.z, hv.z,a2); a3=fmaf(q7.w, hv.w,a3);
                    hv=h4[8];  a0=fmaf(q8.x, hv.x,a0); a1=fmaf(q8.y, hv.y,a1); a2=fmaf(q8.z, hv.z,a2); a3=fmaf(q8.w, hv.w,a3);
                    hv=h4[9];  a0=fmaf(q9.x, hv.x,a0); a1=fmaf(q9.y, hv.y,a1); a2=fmaf(q9.z, hv.z,a2); a3=fmaf(q9.w, hv.w,a3);
                    hv=h4[10]; a0=fmaf(q10.x,hv.x,a0); a1=fmaf(q10.y,hv.y,a1); a2=fmaf(q10.z,hv.z,a2); a3=fmaf(q10.w,hv.w,a3);
                    hv=h4[11]; a0=fmaf(q11.x,hv.x,a0); a1=fmaf(q11.y,hv.y,a1); a2=fmaf(q11.z,hv.z,a2); a3=fmaf(q11.w,hv.w,a3);
                    float part = (a0 + a1) + (a2 + a3);
                    if (halfx) ph_sh[g] = part;
                    __syncthreads();
                    if (!halfx) xpd[(size_t)(t0 + tt) * G4 + g] = part + ph_sh[g];
                    __syncthreads();
                }
            }
            __threadfence();
            __syncthreads();
            if (tid == 0) SIGNAL(&flag1[bidx], k + 1)
        }
    } else if (role == 2) {
        // =================== consumer: L1 scan only ===================
        const float4* WA = reinterpret_cast<const float4*>(Whh1 + (size_t)rp * HDIM + cs);
        const float4* WB = reinterpret_cast<const float4*>(Whh1 + (size_t)(rp + 192) * HDIM + cs);
        W6(WDECL) W6(WLOAD) W6(WPIN)

        float hU = h0v[HDIM + e];
        float cU = c0v[HDIM + e];

#pragma unroll 1
        for (int k = 0; k < NCH; ++k) {
            if (tid == 0) {
                WAIT_GE(&flag1[bidx], k + 1)
                if (k >= 2) WAIT_GE(&flag3[bidx], k - 1)   // h1 slot free
            }
            __syncthreads();
            __threadfence();

            const float* xpd = xpbuf + ((size_t)bidx * 2 + (k & 1)) * TCH * G4;
            float*       h1c = h1buf + ((size_t)bidx * 2 + (k & 1)) * TCH * HDIM;

            float xc0 = 0.f, xc1 = 0.f;
            if (comb) { xc0 = xpd[rp]; xc1 = xpd[rp + 192]; }

#pragma unroll 1
            for (int t = 0; t < TCH; ++t) {
                float xn0 = 0.f, xn1 = 0.f;
                if (comb && (t + 1 < TCH)) {
                    const float* nx = xpd + (size_t)(t + 1) * G4;
                    xn0 = nx[rp]; xn1 = nx[rp + 192];
                }
                float a0 = comb ? xc0 : 0.f;
                float a1 = comb ? xc1 : 0.f;
                float a0b = 0.f, a1b = 0.f;
                MV_ALL()
                float g0 = a0 + a0b, g1 = a1 + a1b;

                if (!comb) part_sh[colseg - 1][rp] = make_float2(g0, g1);
                __syncthreads();
                if (comb) {
                    float2 q0 = part_sh[0][rp], q1 = part_sh[1][rp], q2 = part_sh[2][rp];
                    g0 += (q0.x + q1.x) + q2.x;
                    g1 += (q0.y + q1.y) + q2.y;
                    float s0 = 1.f / (1.f + __expf(-g0));
                    if (rp < 96) {
                        float tg = 2.f / (1.f + __expf(-2.f * g1)) - 1.f;
                        p_sh[rp] = s0 * tg;
                    } else {
                        float s1 = 1.f / (1.f + __expf(-g1));
                        fo_sh[rp - 96] = make_float2(s0, s1);
                    }
                }
                __syncthreads();

                float  p  = p_sh[e];
                float2 fo = fo_sh[e];
                cU = fmaf(fo.x, cU, p);
                hU = fo.y * tanh_(cU);
                if (hstore) h1c[(size_t)t * HDIM + e] = hU;
                xc0 = xn0; xc1 = xn1;
            }
            __threadfence();
            __syncthreads();
            if (tid == 0) SIGNAL(&flag2[bidx], k + 1)
        }
    } else {
        // =================== head ===================
        const float hb = headb[0];
        float4 wv0=reinterpret_cast<const float4*>(headw)[0];
        float4 wv[24];
#pragma unroll
        for (int j = 0; j < 24; ++j) wv[j] = reinterpret_cast<const float4*>(headw)[j];
        (void)wv0;

#pragma unroll 1
        for (int k = 0; k < NCH; ++k) {
            if (tid == 0) WAIT_GE(&flag2[bidx], k + 1)
            __syncthreads();
            __threadfence();

            const float* h1c = h1buf + ((size_t)bidx * 2 + (k & 1)) * TCH * HDIM;
            for (int t = tid; t < TCH; t += 768) {
                const float4* hp = reinterpret_cast<const float4*>(h1c + (size_t)t * HDIM);
                float s2 = 0.f;
#pragma unroll
                for (int j = 0; j < 24; ++j) {
                    float4 a = hp[j], b = wv[j];
                    s2 = fmaf(a.x, b.x, s2); s2 = fmaf(a.y, b.y, s2);
                    s2 = fmaf(a.z, b.z, s2); s2 = fmaf(a.w, b.w, s2);
                }
                out[(size_t)bidx * LSEQ + (size_t)k * TCH + t] = s2 + hb;
            }
            __threadfence();
            __syncthreads();
            if (tid == 0) SIGNAL(&flag3[bidx], k + 1)
        }
    }
}

// ---------------------------------------------------------------------------
extern "C" void kernel_launch(void* const* d_in, const int* in_sizes, int n_in,
                              void* d_out, int out_size, void* d_ws, size_t ws_size,
                              hipStream_t stream)
{
    const float* x     = (const float*)d_in[0];
    const float* Wih0  = (const float*)d_in[1];
    const float* Whh0  = (const float*)d_in[2];
    const float* b0    = (const float*)d_in[3];
    const float* Wih1  = (const float*)d_in[4];
    const float* Whh1  = (const float*)d_in[5];
    const float* b1    = (const float*)d_in[6];
    const float* h0    = (const float*)d_in[7];
    const float* c0    = (const float*)d_in[8];
    const float* headw = (const float*)d_in[9];
    const float* headb = (const float*)d_in[10];
    float* out = (float*)d_out;

    char* ws = (char*)d_ws;
    const size_t h0bytes = (size_t)BATCH * LSEQ * HDIM * sizeof(float);    // 100.7 MB
    const size_t xpbytes = (size_t)BATCH * 2 * TCH * G4 * sizeof(float);   // 25.2 MB
    const size_t h1bytes = (size_t)BATCH * 2 * TCH * HDIM * sizeof(float); // 6.3 MB

    float* h0buf = (float*)ws;
    float* xpbuf = (float*)(ws + h0bytes);
    float* h1buf = (float*)(ws + h0bytes + xpbytes);
    int*   flags = (int*)  (ws + h0bytes + xpbytes + h1bytes);

    init_flags<<<1, 64, 0, stream>>>(flags);
    lstm_pipe<<<32, 768, 0, stream>>>(x, Wih0, Whh0, b0, Wih1, Whh1, b1,
                                      h0, c0, headw, headb,
                                      h0buf, xpbuf, h1buf, flags, out);
}

// Round 13
// 19890.123 us; speedup vs baseline: 4.2705x; 1.4024x over previous
//
#include <hip/hip_runtime.h>

#define HDIM 96
#define G4   384
#define LSEQ 32768
#define BATCH 8
#define TCH   1024
#define NCH   (LSEQ / TCH)

__device__ __forceinline__ float sigm_(float x) {
    return __builtin_amdgcn_rcpf(1.f + __expf(-x));
}
__device__ __forceinline__ float tanh_(float x) {
    return fmaf(-2.f, __builtin_amdgcn_rcpf(1.f + __expf(2.f * x)), 1.f);
}

// 8-lane butterfly sum on the VALU pipe (DPP), zero DS-pipe usage.
// Stages: xor1 = quad_perm(1,0,3,2)=0xB1, xor2 = quad_perm(2,3,0,1)=0x4E,
// then row_half_mirror (0x141) completes the 8-lane sum (quads uniform).
#define DPPSTEP(v, CTRL) { \
    int t_ = __builtin_amdgcn_update_dpp(0, __float_as_int(v), CTRL, 0xF, 0xF, true); \
    v += __int_as_float(t_); }
#define RED8(v) DPPSTEP(v, 0xB1) DPPSTEP(v, 0x4E) DPPSTEP(v, 0x141)

#define PIN4x3(A,B,C) asm volatile("" : \
  "+v"(A.x),"+v"(A.y),"+v"(A.z),"+v"(A.w), \
  "+v"(B.x),"+v"(B.y),"+v"(B.z),"+v"(B.w), \
  "+v"(C.x),"+v"(C.y),"+v"(C.z),"+v"(C.w));

// Thread owns all 4 gate rows of element e x cols [12s, 12s+12).
#define WLOADPIN(W) \
    const float4* pI = reinterpret_cast<const float4*>((W) + (size_t)e        * HDIM + 12*s); \
    const float4* pF = reinterpret_cast<const float4*>((W) + (size_t)(96 + e) * HDIM + 12*s); \
    const float4* pG = reinterpret_cast<const float4*>((W) + (size_t)(192+ e) * HDIM + 12*s); \
    const float4* pO = reinterpret_cast<const float4*>((W) + (size_t)(288+ e) * HDIM + 12*s); \
    float4 wI0=pI[0], wI1=pI[1], wI2=pI[2]; \
    float4 wF0=pF[0], wF1=pF[1], wF2=pF[2]; \
    float4 wG0=pG[0], wG1=pG[1], wG2=pG[2]; \
    float4 wO0=pO[0], wO1=pO[1], wO2=pO[2]; \
    PIN4x3(wI0,wI1,wI2) PIN4x3(wF0,wF1,wF2) PIN4x3(wG0,wG1,wG2) PIN4x3(wO0,wO1,wO2)

#define MVK(n, hv) \
  gi=fmaf(wI##n.x,hv.x,gi); gi=fmaf(wI##n.y,hv.y,gi); gi=fmaf(wI##n.z,hv.z,gi); gi=fmaf(wI##n.w,hv.w,gi); \
  gf=fmaf(wF##n.x,hv.x,gf); gf=fmaf(wF##n.y,hv.y,gf); gf=fmaf(wF##n.z,hv.z,gf); gf=fmaf(wF##n.w,hv.w,gf); \
  gg=fmaf(wG##n.x,hv.x,gg); gg=fmaf(wG##n.y,hv.y,gg); gg=fmaf(wG##n.z,hv.z,gg); gg=fmaf(wG##n.w,hv.w,gg); \
  go=fmaf(wO##n.x,hv.x,go); go=fmaf(wO##n.y,hv.y,go); go=fmaf(wO##n.z,hv.z,go); go=fmaf(wO##n.w,hv.w,go);

#define WAIT_GE(PTR, VAL) \
    while (__hip_atomic_load((PTR), __ATOMIC_ACQUIRE, __HIP_MEMORY_SCOPE_AGENT) < (VAL)) \
        __builtin_amdgcn_s_sleep(2);

#define SIGNAL(PTR, VAL) \
    __hip_atomic_store((PTR), (VAL), __ATOMIC_RELEASE, __HIP_MEMORY_SCOPE_AGENT);

__global__ void init_flags(int* flags) {
    if (threadIdx.x < 64) flags[threadIdx.x] = 0;
}

// ---------------------------------------------------------------------------
// 32 blocks, 4 roles:
//   0..7   producer : L0 scan (DPP core) -> h0buf, flag0 per TCH chunk
//   8..15  xp worker: flag0 -> xp ring depth 2 in (t,e,gate)-float4, flag1
//   16..23 consumer : flag1 -> L1 scan (DPP core) -> h1 ring, flag2
//   24..31 head     : flag2 -> out, flag3 (h1 slot reuse)
// Scan core: tid = e*8+s; one barrier/step; butterfly via DPP (VALU pipe);
// h double-buffered in LDS; c redundant per-lane in registers.
// Bias / input-projection terms are added ONCE, after RED8 (all lanes add
// the same value to the already-uniform reduced sum).
// ---------------------------------------------------------------------------
__global__ void __launch_bounds__(768)
__attribute__((amdgpu_waves_per_eu(3, 3)))
lstm_pipe(const float* __restrict__ x,
          const float* __restrict__ Wih0, const float* __restrict__ Whh0, const float* __restrict__ b0v,
          const float* __restrict__ Wih1, const float* __restrict__ Whh1, const float* __restrict__ b1v,
          const float* __restrict__ h0v,  const float* __restrict__ c0v,
          const float* __restrict__ headw,const float* __restrict__ headb,
          float* __restrict__ h0buf, float* __restrict__ xpbuf, float* __restrict__ h1buf,
          int* flags, float* __restrict__ out)
{
    const int tid  = threadIdx.x;
    const int lane = tid & 63;
    const int e    = tid >> 3;     // element 0..95
    const int s    = tid & 7;      // 12-col segment 0..7
    const bool w0l = ((lane & 7) == 0);

    int* flag0 = flags;
    int* flag1 = flags + 8;
    int* flag2 = flags + 16;
    int* flag3 = flags + 24;

    __shared__ __align__(16) float hs[2 * HDIM];
    __shared__ __align__(16) float h_sh[32 * HDIM];
    __shared__ float ph_sh[G4];

    const int role = blockIdx.x >> 3;
    const int bidx = blockIdx.x & 7;

    if (role == 0) {
        // =================== producer: L0 scan ===================
        WLOADPIN(Whh0)
        const float wiI = Wih0[e],  wiF = Wih0[96+e],  wiG = Wih0[192+e],  wiO = Wih0[288+e];
        const float bbI = b0v[e],   bbF = b0v[96+e],   bbG = b0v[192+e],   bbO = b0v[288+e];

        float cU = c0v[e];
        if (w0l) hs[e] = h0v[e];
        __syncthreads();

        const float* xb  = x + (size_t)bidx * LSEQ;
        float*       hob = h0buf + (size_t)bidx * LSEQ * HDIM;
        float xt = xb[0];
        int rOff = 0;

#pragma unroll 1
        for (int t = 0; t < LSEQ; ++t) {
            int tn = (t + 1 < LSEQ) ? t + 1 : LSEQ - 1;
            float xnext = xb[tn];

            const float4* hp = reinterpret_cast<const float4*>(hs + rOff + 12 * s);
            float4 hv0 = hp[0], hv1 = hp[1], hv2 = hp[2];

            float gi = 0.f, gf = 0.f, gg = 0.f, go = 0.f;
            MVK(0, hv0) MVK(1, hv1) MVK(2, hv2)
            RED8(gi) RED8(gf) RED8(gg) RED8(go)
            // bias + input term added ONCE, post-reduction (uniform per lane)
            gi += fmaf(wiI, xt, bbI);
            gf += fmaf(wiF, xt, bbF);
            gg += fmaf(wiG, xt, bbG);
            go += fmaf(wiO, xt, bbO);

            float si = sigm_(gi), sf = sigm_(gf), tg = tanh_(gg), so = sigm_(go);
            cU = fmaf(sf, cU, si * tg);
            float hN = so * tanh_(cU);

            if (w0l) {
                hs[(rOff ^ HDIM) + e] = hN;
                hob[(size_t)t * HDIM + e] = hN;
            }
            rOff ^= HDIM;
            xt = xnext;

            if (((t + 1) & (TCH - 1)) == 0) {
                __threadfence();
                __syncthreads();
                if (tid == 0) SIGNAL(&flag0[bidx], (t + 1) / TCH)
            }
            __syncthreads();
        }
    } else if (role == 1) {
        // =================== xp worker ===================
        const bool halfx = (tid >= G4);
        const int  g     = halfx ? tid - G4 : tid;
        const int  dstoff = (g % 96) * 4 + (g / 96);   // (e,gate) float4 layout
        const float4* Wxp = reinterpret_cast<const float4*>(Wih1 + (size_t)g * HDIM + (halfx ? 48 : 0));
        const float xbias = halfx ? 0.f : b1v[g];

        float4 q0=Wxp[0],q1=Wxp[1],q2=Wxp[2],q3=Wxp[3],q4=Wxp[4],q5=Wxp[5],
               q6=Wxp[6],q7=Wxp[7],q8=Wxp[8],q9=Wxp[9],q10=Wxp[10],q11=Wxp[11];
        PIN4x3(q0,q1,q2) PIN4x3(q3,q4,q5) PIN4x3(q6,q7,q8) PIN4x3(q9,q10,q11)

        const float* hsrcB = h0buf + (size_t)bidx * LSEQ * HDIM;

#pragma unroll 1
        for (int k = 0; k < NCH; ++k) {
            if (tid == 0) {
                WAIT_GE(&flag0[bidx], k + 1)
                if (k >= 2) WAIT_GE(&flag2[bidx], k - 1)
            }
            __syncthreads();
            __threadfence();

            const float* hsrc = hsrcB + (size_t)k * TCH * HDIM;
            float* xpd = xpbuf + ((size_t)bidx * 2 + (k & 1)) * TCH * G4;

#pragma unroll 1
            for (int t0 = 0; t0 < TCH; t0 += 32) {
                for (int i = tid; i < 32 * HDIM; i += 768)
                    h_sh[i] = hsrc[(size_t)t0 * HDIM + i];
                __syncthreads();
#pragma unroll 1
                for (int tt = 0; tt < 32; ++tt) {
                    const float4* h4 = reinterpret_cast<const float4*>(
                        h_sh + tt * HDIM + (halfx ? 48 : 0));
                    float a0 = xbias, a1 = 0.f, a2 = 0.f, a3 = 0.f;
                    float4 hv;
                    hv=h4[0];  a0=fmaf(q0.x, hv.x,a0); a1=fmaf(q0.y, hv.y,a1); a2=fmaf(q0.z, hv.z,a2); a3=fmaf(q0.w, hv.w,a3);
                    hv=h4[1];  a0=fmaf(q1.x, hv.x,a0); a1=fmaf(q1.y, hv.y,a1); a2=fmaf(q1.z, hv.z,a2); a3=fmaf(q1.w, hv.w,a3);
                    hv=h4[2];  a0=fmaf(q2.x, hv.x,a0); a1=fmaf(q2.y, hv.y,a1); a2=fmaf(q2.z, hv.z,a2); a3=fmaf(q2.w, hv.w,a3);
                    hv=h4[3];  a0=fmaf(q3.x, hv.x,a0); a1=fmaf(q3.y, hv.y,a1); a2=fmaf(q3.z, hv.z,a2); a3=fmaf(q3.w, hv.w,a3);
                    hv=h4[4];  a0=fmaf(q4.x, hv.x,a0); a1=fmaf(q4.y, hv.y,a1); a2=fmaf(q4.z, hv.z,a2); a3=fmaf(q4.w, hv.w,a3);
                    hv=h4[5];  a0=fmaf(q5.x, hv.x,a0); a1=fmaf(q5.y, hv.y,a1); a2=fmaf(q5.z, hv.z,a2); a3=fmaf(q5.w, hv.w,a3);
                    hv=h4[6];  a0=fmaf(q6.x, hv.x,a0); a1=fmaf(q6.y, hv.y,a1); a2=fmaf(q6.z, hv.z,a2); a3=fmaf(q6.w, hv.w,a3);
                    hv=h4[7];  a0=fmaf(q7.x, hv.x,a0); a1=fmaf(q7.y, hv.y,a1); a2=fmaf(q7.z, hv.z,a2); a3=fmaf(q7.w, hv.w,a3);
                    hv=h4[8];  a0=fmaf(q8.x, hv.x,a0); a1=fmaf(q8.y, hv.y,a1); a2=fmaf(q8.z, hv.z,a2); a3=fmaf(q8.w, hv.w,a3);
                    hv=h4[9];  a0=fmaf(q9.x, hv.x,a0); a1=fmaf(q9.y, hv.y,a1); a2=fmaf(q9.z, hv.z,a2); a3=fmaf(q9.w, hv.w,a3);
                    hv=h4[10]; a0=fmaf(q10.x,hv.x,a0); a1=fmaf(q10.y,hv.y,a1); a2=fmaf(q10.z,hv.z,a2); a3=fmaf(q10.w,hv.w,a3);
                    hv=h4[11]; a0=fmaf(q11.x,hv.x,a0); a1=fmaf(q11.y,hv.y,a1); a2=fmaf(q11.z,hv.z,a2); a3=fmaf(q11.w,hv.w,a3);
                    float part = (a0 + a1) + (a2 + a3);
                    if (halfx) ph_sh[g] = part;
                    __syncthreads();
                    if (!halfx) xpd[(size_t)(t0 + tt) * G4 + dstoff] = part + ph_sh[g];
                    __syncthreads();
                }
            }
            __threadfence();
            __syncthreads();
            if (tid == 0) SIGNAL(&flag1[bidx], k + 1)
        }
    } else if (role == 2) {
        // =================== consumer: L1 scan ===================
        WLOADPIN(Whh1)

        float cU = c0v[HDIM + e];
        if (w0l) hs[e] = h0v[HDIM + e];
        __syncthreads();
        int rOff = 0;

#pragma unroll 1
        for (int k = 0; k < NCH; ++k) {
            if (tid == 0) {
                WAIT_GE(&flag1[bidx], k + 1)
                if (k >= 2) WAIT_GE(&flag3[bidx], k - 1)
            }
            __syncthreads();
            __threadfence();

            const float4* xq  = reinterpret_cast<const float4*>(
                xpbuf + ((size_t)bidx * 2 + (k & 1)) * TCH * G4) + e;
            float* h1c = h1buf + ((size_t)bidx * 2 + (k & 1)) * TCH * HDIM;

            float4 xp4 = xq[0];

#pragma unroll 1
            for (int t = 0; t < TCH; ++t) {
                int tn = (t + 1 < TCH) ? t + 1 : TCH - 1;
                float4 xpn = xq[(size_t)tn * HDIM];

                const float4* hp = reinterpret_cast<const float4*>(hs + rOff + 12 * s);
                float4 hv0 = hp[0], hv1 = hp[1], hv2 = hp[2];

                float gi = 0.f, gf = 0.f, gg = 0.f, go = 0.f;
                MVK(0, hv0) MVK(1, hv1) MVK(2, hv2)
                RED8(gi) RED8(gf) RED8(gg) RED8(go)
                // xp (bias folded) added ONCE, post-reduction
                gi += xp4.x; gf += xp4.y; gg += xp4.z; go += xp4.w;

                float si = sigm_(gi), sf = sigm_(gf), tg = tanh_(gg), so = sigm_(go);
                cU = fmaf(sf, cU, si * tg);
                float hN = so * tanh_(cU);

                if (w0l) {
                    hs[(rOff ^ HDIM) + e] = hN;
                    h1c[(size_t)t * HDIM + e] = hN;
                }
                rOff ^= HDIM;
                xp4 = xpn;
                __syncthreads();
            }
            __threadfence();
            __syncthreads();
            if (tid == 0) SIGNAL(&flag2[bidx], k + 1)
        }
    } else {
        // =================== head ===================
        const float hb = headb[0];
        float4 wv[24];
#pragma unroll
        for (int j = 0; j < 24; ++j) wv[j] = reinterpret_cast<const float4*>(headw)[j];

#pragma unroll 1
        for (int k = 0; k < NCH; ++k) {
            if (tid == 0) WAIT_GE(&flag2[bidx], k + 1)
            __syncthreads();
            __threadfence();

            const float* h1c = h1buf + ((size_t)bidx * 2 + (k & 1)) * TCH * HDIM;
            for (int t = tid; t < TCH; t += 768) {
                const float4* hp = reinterpret_cast<const float4*>(h1c + (size_t)t * HDIM);
                float s2 = 0.f;
#pragma unroll
                for (int j = 0; j < 24; ++j) {
                    float4 a = hp[j], b = wv[j];
                    s2 = fmaf(a.x, b.x, s2); s2 = fmaf(a.y, b.y, s2);
                    s2 = fmaf(a.z, b.z, s2); s2 = fmaf(a.w, b.w, s2);
                }
                out[(size_t)bidx * LSEQ + (size_t)k * TCH + t] = s2 + hb;
            }
            __threadfence();
            __syncthreads();
            if (tid == 0) SIGNAL(&flag3[bidx], k + 1)
        }
    }
}

// ---------------------------------------------------------------------------
extern "C" void kernel_launch(void* const* d_in, const int* in_sizes, int n_in,
                              void* d_out, int out_size, void* d_ws, size_t ws_size,
                              hipStream_t stream)
{
    const float* x     = (const float*)d_in[0];
    const float* Wih0  = (const float*)d_in[1];
    const float* Whh0  = (const float*)d_in[2];
    const float* b0    = (const float*)d_in[3];
    const float* Wih1  = (const float*)d_in[4];
    const float* Whh1  = (const float*)d_in[5];
    const float* b1    = (const float*)d_in[6];
    const float* h0    = (const float*)d_in[7];
    const float* c0    = (const float*)d_in[8];
    const float* headw = (const float*)d_in[9];
    const float* headb = (const float*)d_in[10];
    float* out = (float*)d_out;

    char* ws = (char*)d_ws;
    const size_t h0bytes = (size_t)BATCH * LSEQ * HDIM * sizeof(float);    // 100.7 MB
    const size_t xpbytes = (size_t)BATCH * 2 * TCH * G4 * sizeof(float);   // 25.2 MB
    const size_t h1bytes = (size_t)BATCH * 2 * TCH * HDIM * sizeof(float); // 6.3 MB

    float* h0buf = (float*)ws;
    float* xpbuf = (float*)(ws + h0bytes);
    float* h1buf = (float*)(ws + h0bytes + xpbytes);
    int*   flags = (int*)  (ws + h0bytes + xpbytes + h1bytes);

    init_flags<<<1, 64, 0, stream>>>(flags);
    lstm_pipe<<<32, 768, 0, stream>>>(x, Wih0, Whh0, b0, Wih1, Whh1, b1,
                                      h0, c0, headw, headb,
                                      h0buf, xpbuf, h1buf, flags, out);
}